// Round 1
// baseline (833.971 us; speedup 1.0000x reference)
//
#include <hip/hip_runtime.h>

typedef float f32x4 __attribute__((ext_vector_type(4)));
typedef short s16x8 __attribute__((ext_vector_type(8)));

#define MFMA16(a, b, c) __builtin_amdgcn_mfma_f32_16x16x32_bf16((a), (b), (c), 0, 0, 0)

static __device__ __forceinline__ unsigned short f2bf(float f) {
    unsigned int u = __float_as_uint(f);
    u += 0x7fffu + ((u >> 16) & 1u);   // round-to-nearest-even
    return (unsigned short)(u >> 16);
}
static __device__ __forceinline__ float bf2f(unsigned short h) {
    return __uint_as_float(((unsigned int)h) << 16);
}

// ---------------------------------------------------------------- CPB MLP ---
// t2[row][h] = (relu(t @ w1 + b1) @ w2)[row][h],  row in [0,529), h in [0,12)
__global__ __launch_bounds__(128) void cpb_kernel(
    const float* __restrict__ tbl,   // [529*2]
    const float* __restrict__ w1,    // [2*512]
    const float* __restrict__ b1,    // [512]
    const float* __restrict__ w2,    // [512*12]
    float* __restrict__ t2)          // [529*12]
{
    const int row = blockIdx.x;
    const int tid = threadIdx.x;
    const float t0 = tbl[row * 2 + 0];
    const float t1 = tbl[row * 2 + 1];
    float part[12];
#pragma unroll
    for (int h = 0; h < 12; h++) part[h] = 0.f;
    for (int j = tid; j < 512; j += 128) {
        float hj = fmaxf(t0 * w1[j] + t1 * w1[512 + j] + b1[j], 0.f);
#pragma unroll
        for (int h = 0; h < 12; h++) part[h] += hj * w2[j * 12 + h];
    }
    __shared__ float red[128][12];
#pragma unroll
    for (int h = 0; h < 12; h++) red[tid][h] = part[h];
    __syncthreads();
    if (tid < 12) {
        float s = 0.f;
        for (int i = 0; i < 128; i++) s += red[i][tid];
        t2[row * 12 + tid] = s;
    }
}

// ---------------------------------------------------------------- QKV GEMM --
// X[73728,384] @ W[384,1152] + bias -> split into Q/K/V [512][12][144][32] bf16
__global__ __launch_bounds__(256) void qkv_gemm(
    const float* __restrict__ X, const float* __restrict__ W,
    const float* __restrict__ Bias,
    unsigned short* __restrict__ Qw, unsigned short* __restrict__ Kw,
    unsigned short* __restrict__ Vw)
{
    __shared__ unsigned short As[64][40];   // [m][k], pad->2-way bank alias
    __shared__ unsigned short Bs[64][40];   // transposed: [n][k]
    const int tid = threadIdx.x;
    const int lane = tid & 63;
    const int wv = tid >> 6;
    const int wm = wv >> 1, wn = wv & 1;
    const int mb = blockIdx.y * 64;
    const int nb = blockIdx.x * 64;
    const int ar = tid >> 2, ac = (tid & 3) * 8;
    const int bk = tid >> 3, bc = (tid & 7) * 8;
    const int rr = lane & 15, ko = (lane >> 4) * 8;

    f32x4 acc00{}, acc01{}, acc10{}, acc11{};

    for (int kb = 0; kb < 384; kb += 32) {
        __syncthreads();
        {   // stage A tile 64x32 (f32 -> bf16)
            const float* src = X + (size_t)(mb + ar) * 384 + kb + ac;
            float4 v0 = *(const float4*)src;
            float4 v1 = *(const float4*)(src + 4);
            s16x8 p;
            p[0] = (short)f2bf(v0.x); p[1] = (short)f2bf(v0.y);
            p[2] = (short)f2bf(v0.z); p[3] = (short)f2bf(v0.w);
            p[4] = (short)f2bf(v1.x); p[5] = (short)f2bf(v1.y);
            p[6] = (short)f2bf(v1.z); p[7] = (short)f2bf(v1.w);
            *(s16x8*)&As[ar][ac] = p;
        }
        {   // stage B tile 32x64 transposed
            const float* src = W + (size_t)(kb + bk) * 1152 + nb + bc;
            float4 v0 = *(const float4*)src;
            float4 v1 = *(const float4*)(src + 4);
            unsigned short tmp[8] = {f2bf(v0.x), f2bf(v0.y), f2bf(v0.z), f2bf(v0.w),
                                     f2bf(v1.x), f2bf(v1.y), f2bf(v1.z), f2bf(v1.w)};
#pragma unroll
            for (int i = 0; i < 8; i++) Bs[bc + i][bk] = tmp[i];
        }
        __syncthreads();
        s16x8 a0 = *(const s16x8*)&As[wm * 32 + rr][ko];
        s16x8 a1 = *(const s16x8*)&As[wm * 32 + 16 + rr][ko];
        s16x8 b0 = *(const s16x8*)&Bs[wn * 32 + rr][ko];
        s16x8 b1 = *(const s16x8*)&Bs[wn * 32 + 16 + rr][ko];
        acc00 = MFMA16(a0, b0, acc00);
        acc01 = MFMA16(a0, b1, acc01);
        acc10 = MFMA16(a1, b0, acc10);
        acc11 = MFMA16(a1, b1, acc11);
    }

#pragma unroll
    for (int fm = 0; fm < 2; fm++) {
#pragma unroll
        for (int fn = 0; fn < 2; fn++) {
            f32x4 a = (fm == 0) ? ((fn == 0) ? acc00 : acc01)
                                : ((fn == 0) ? acc10 : acc11);
            const int c = nb + wn * 32 + fn * 16 + rr;
            const int which = c / 384;
            const int rem = c - which * 384;
            const int h = rem >> 5, d = rem & 31;
            unsigned short* dst = (which == 0) ? Qw : ((which == 1) ? Kw : Vw);
            const float bias = Bias[c];
#pragma unroll
            for (int r = 0; r < 4; r++) {
                const int m = mb + wm * 32 + fm * 16 + (lane >> 4) * 4 + r;
                const int b = m / 144;
                const int n = m - b * 144;
                dst[(((size_t)b * 12 + h) * 144 + n) * 32 + d] = f2bf(a[r] + bias);
            }
        }
    }
}

// ---------------------------------------------------------------- Attention -
// one block per (b,h); 9 waves; wave w owns query rows 16w..16w+15
__global__ __launch_bounds__(576) void attn_kernel(
    const unsigned short* __restrict__ Qw, const unsigned short* __restrict__ Kw,
    const unsigned short* __restrict__ Vw,
    const float* __restrict__ mask,          // [64][144][144]
    const float* __restrict__ logit_scale,   // [12]
    const float* __restrict__ t2,            // [529][12]
    const int* __restrict__ idx,             // [144][144]
    unsigned short* __restrict__ Ow)         // [73728][384] bf16
{
    __shared__ unsigned short Qs[144][40];
    __shared__ unsigned short Ks[144][40];
    __shared__ unsigned short Vt[32][168];   // transposed V: [d][j], j padded to 160
    __shared__ unsigned short Ps[9][16][40]; // per-wave P slice: 16 rows x 32 k
    __shared__ float qin[144], kin[144];

    const int blk = blockIdx.x;
    const int b = blk / 12, h = blk - (blk / 12) * 12;
    const int tid = threadIdx.x;
    const int wv = tid >> 6, lane = tid & 63;
    const int rr = lane & 15, g = lane >> 4, ko = g * 8;

    const size_t base = ((size_t)b * 12 + h) * 144 * 32;
    const unsigned short* Qg = Qw + base;
    const unsigned short* Kg = Kw + base;
    const unsigned short* Vg = Vw + base;

    for (int e = tid; e < 4608; e += 576) {
        const int r = e >> 5, c = e & 31;
        Qs[r][c] = Qg[e];
        Ks[r][c] = Kg[e];
        Vt[c][r] = Vg[e];
    }
    for (int e = tid; e < 512; e += 576) Vt[e >> 4][144 + (e & 15)] = 0;  // pad k
    __syncthreads();

    if (tid < 288) {                         // row norms from the bf16 values
        const int r = (tid < 144) ? tid : tid - 144;
        const unsigned short* src = (tid < 144) ? &Qs[r][0] : &Ks[r][0];
        float acc = 0.f;
#pragma unroll
        for (int c2 = 0; c2 < 32; c2++) { float f = bf2f(src[c2]); acc += f * f; }
        const float inv = rsqrtf(acc);
        if (tid < 144) {
            const float lsv = expf(fminf(logit_scale[h], 4.60517019f)); // log(100)
            qin[r] = inv * lsv;              // fold logit scale into q side
        } else {
            kin[r] = inv;
        }
    }
    __syncthreads();

    // ---- S = q . k^T (unnormalized), 9 col tiles
    const s16x8 aq = *(const s16x8*)&Qs[wv * 16 + rr][ko];
    f32x4 s[9];
#pragma unroll
    for (int j = 0; j < 9; j++) {
        const s16x8 bkf = *(const s16x8*)&Ks[j * 16 + rr][ko];
        f32x4 z{};
        s[j] = MFMA16(aq, bkf, z);
    }

    // ---- softmax (logit = S*qin*kin + 16*sigmoid(cpb) + mask)
    const int win = b & 63;
    const float* mrow = mask + (size_t)win * 20736;
    const int rowbase = wv * 16 + g * 4;
    float pv[4][9];
    float invsum[4];
#pragma unroll
    for (int r = 0; r < 4; r++) {
        const int ri = rowbase + r;
        const float qi = qin[ri];
        float lg[9];
        float mx = -3.0e38f;
#pragma unroll
        for (int j = 0; j < 9; j++) {
            const int cj = j * 16 + rr;
            float bias = t2[idx[ri * 144 + cj] * 12 + h];
            bias = 16.f / (1.f + __expf(-bias));
            const float lv = s[j][r] * qi * kin[cj] + bias + mrow[ri * 144 + cj];
            lg[j] = lv;
            mx = fmaxf(mx, lv);
        }
#pragma unroll
        for (int o = 1; o < 16; o <<= 1) mx = fmaxf(mx, __shfl_xor(mx, o, 64));
        float sm = 0.f;
#pragma unroll
        for (int j = 0; j < 9; j++) {
            const float p = __expf(lg[j] - mx);
            pv[r][j] = p;
            sm += p;
        }
#pragma unroll
        for (int o = 1; o < 16; o <<= 1) sm += __shfl_xor(sm, o, 64);
        invsum[r] = 1.f / sm;
    }

    // ---- PV: O[16x32] += P[16x144(pad160)] @ V[144x32], 32 k at a time
    f32x4 o0{}, o1{};
#pragma unroll
    for (int kt = 0; kt < 5; kt++) {
#pragma unroll
        for (int jj = 0; jj < 2; jj++) {
            const int j = 2 * kt + jj;
#pragma unroll
            for (int r = 0; r < 4; r++) {
                const unsigned short val = (j < 9) ? f2bf(pv[r][j]) : (unsigned short)0;
                Ps[wv][g * 4 + r][jj * 16 + rr] = val;
            }
        }
        const s16x8 pa  = *(const s16x8*)&Ps[wv][rr][ko];
        const s16x8 vb0 = *(const s16x8*)&Vt[rr][kt * 32 + ko];
        const s16x8 vb1 = *(const s16x8*)&Vt[16 + rr][kt * 32 + ko];
        o0 = MFMA16(pa, vb0, o0);
        o1 = MFMA16(pa, vb1, o1);
    }

#pragma unroll
    for (int r = 0; r < 4; r++) {
        const int ri = rowbase + r;
        const size_t orow = ((size_t)b * 144 + ri) * 384 + h * 32;
        Ow[orow + rr]      = f2bf(o0[r] * invsum[r]);
        Ow[orow + 16 + rr] = f2bf(o1[r] * invsum[r]);
    }
}

// ---------------------------------------------------------------- Proj GEMM -
// O[73728,384](bf16) @ W[384,384] + bias -> out f32
__global__ __launch_bounds__(256) void proj_gemm(
    const unsigned short* __restrict__ A, const float* __restrict__ W,
    const float* __restrict__ Bias, float* __restrict__ Out)
{
    __shared__ unsigned short As[64][40];
    __shared__ unsigned short Bs[64][40];
    const int tid = threadIdx.x;
    const int lane = tid & 63;
    const int wv = tid >> 6;
    const int wm = wv >> 1, wn = wv & 1;
    const int mb = blockIdx.y * 64;
    const int nb = blockIdx.x * 64;
    const int ar = tid >> 2, ac = (tid & 3) * 8;
    const int bk = tid >> 3, bc = (tid & 7) * 8;
    const int rr = lane & 15, ko = (lane >> 4) * 8;

    f32x4 acc00{}, acc01{}, acc10{}, acc11{};

    for (int kb = 0; kb < 384; kb += 32) {
        __syncthreads();
        *(uint4*)&As[ar][ac] = *(const uint4*)(A + (size_t)(mb + ar) * 384 + kb + ac);
        {
            const float* src = W + (size_t)(kb + bk) * 384 + nb + bc;
            float4 v0 = *(const float4*)src;
            float4 v1 = *(const float4*)(src + 4);
            unsigned short tmp[8] = {f2bf(v0.x), f2bf(v0.y), f2bf(v0.z), f2bf(v0.w),
                                     f2bf(v1.x), f2bf(v1.y), f2bf(v1.z), f2bf(v1.w)};
#pragma unroll
            for (int i = 0; i < 8; i++) Bs[bc + i][bk] = tmp[i];
        }
        __syncthreads();
        s16x8 a0 = *(const s16x8*)&As[wm * 32 + rr][ko];
        s16x8 a1 = *(const s16x8*)&As[wm * 32 + 16 + rr][ko];
        s16x8 b0 = *(const s16x8*)&Bs[wn * 32 + rr][ko];
        s16x8 b1 = *(const s16x8*)&Bs[wn * 32 + 16 + rr][ko];
        acc00 = MFMA16(a0, b0, acc00);
        acc01 = MFMA16(a0, b1, acc01);
        acc10 = MFMA16(a1, b0, acc10);
        acc11 = MFMA16(a1, b1, acc11);
    }

#pragma unroll
    for (int fm = 0; fm < 2; fm++) {
#pragma unroll
        for (int fn = 0; fn < 2; fn++) {
            f32x4 a = (fm == 0) ? ((fn == 0) ? acc00 : acc01)
                                : ((fn == 0) ? acc10 : acc11);
            const int c = nb + wn * 32 + fn * 16 + rr;
            const float bias = Bias[c];
#pragma unroll
            for (int r = 0; r < 4; r++) {
                const int m = mb + wm * 32 + fm * 16 + (lane >> 4) * 4 + r;
                Out[(size_t)m * 384 + c] = a[r] + bias;
            }
        }
    }
}

// ---------------------------------------------------------------- launch ----
extern "C" void kernel_launch(void* const* d_in, const int* in_sizes, int n_in,
                              void* d_out, int out_size, void* d_ws, size_t ws_size,
                              hipStream_t stream)
{
    (void)in_sizes; (void)n_in; (void)out_size; (void)ws_size;
    const float* x           = (const float*)d_in[0];
    const float* mask        = (const float*)d_in[1];
    const float* qkv_w       = (const float*)d_in[2];
    const float* qkv_b       = (const float*)d_in[3];
    const float* proj_w      = (const float*)d_in[4];
    const float* proj_b      = (const float*)d_in[5];
    const float* cpb_w1      = (const float*)d_in[6];
    const float* cpb_b1      = (const float*)d_in[7];
    const float* cpb_w2      = (const float*)d_in[8];
    const float* logit_scale = (const float*)d_in[9];
    const float* tbl         = (const float*)d_in[10];
    const int*   idx         = (const int*)d_in[11];

    char* ws = (char*)d_ws;
    const size_t QELEMS = (size_t)512 * 12 * 144 * 32;      // 28,311,552
    float* t2          = (float*)ws;                        // 25,392 B (pad 25,600)
    unsigned short* Qw = (unsigned short*)(ws + 25600);
    unsigned short* Kw = Qw + QELEMS;
    unsigned short* Vw = Kw + QELEMS;
    unsigned short* Ow = Vw + QELEMS;                       // 73728*384 bf16

    cpb_kernel<<<529, 128, 0, stream>>>(tbl, cpb_w1, cpb_b1, cpb_w2, t2);
    qkv_gemm<<<dim3(18, 1152), 256, 0, stream>>>(x, qkv_w, qkv_b, Qw, Kw, Vw);
    attn_kernel<<<6144, 576, 0, stream>>>(Qw, Kw, Vw, mask, logit_scale, t2, idx, Ow);
    proj_gemm<<<dim3(6, 1152), 256, 0, stream>>>(Ow, proj_w, proj_b, (float*)d_out);
}

// Round 2
// 607.942 us; speedup vs baseline: 1.3718x; 1.3718x over previous
//
#include <hip/hip_runtime.h>

typedef float f32x4 __attribute__((ext_vector_type(4)));
typedef short s16x8 __attribute__((ext_vector_type(8)));
typedef unsigned int u32;

#define MFMA16(a, b, c) __builtin_amdgcn_mfma_f32_16x16x32_bf16((a), (b), (c), 0, 0, 0)

static __device__ __forceinline__ unsigned short f2bf(float f) {
    unsigned int u = __float_as_uint(f);
    u += 0x7fffu + ((u >> 16) & 1u);   // round-to-nearest-even
    return (unsigned short)(u >> 16);
}
static __device__ __forceinline__ float bf2f(unsigned short h) {
    return __uint_as_float(((unsigned int)h) << 16);
}

// async global->LDS, 16B per lane; LDS dest must be wave-uniform base (lane*16 added by HW)
static __device__ __forceinline__ void gload16(const unsigned short* g, unsigned short* l) {
    __builtin_amdgcn_global_load_lds(
        (const __attribute__((address_space(1))) u32*)g,
        (__attribute__((address_space(3))) u32*)l,
        16, 0, 0);
}

// ---------------------------------------------------------------- CPB MLP ---
__global__ __launch_bounds__(128) void cpb_kernel(
    const float* __restrict__ tbl, const float* __restrict__ w1,
    const float* __restrict__ b1, const float* __restrict__ w2,
    float* __restrict__ t2)
{
    const int row = blockIdx.x;
    const int tid = threadIdx.x;
    const float t0 = tbl[row * 2 + 0];
    const float t1 = tbl[row * 2 + 1];
    float part[12];
#pragma unroll
    for (int h = 0; h < 12; h++) part[h] = 0.f;
    for (int j = tid; j < 512; j += 128) {
        float hj = fmaxf(t0 * w1[j] + t1 * w1[512 + j] + b1[j], 0.f);
#pragma unroll
        for (int h = 0; h < 12; h++) part[h] += hj * w2[j * 12 + h];
    }
    __shared__ float red[128][12];
#pragma unroll
    for (int h = 0; h < 12; h++) red[tid][h] = part[h];
    __syncthreads();
    if (tid < 12) {
        float s = 0.f;
        for (int i = 0; i < 128; i++) s += red[i][tid];
        t2[row * 12 + tid] = s;
    }
}

// ------------------------------------------------------- bias12 precompute --
// bias12[h][ij] = 16*sigmoid(t2[idx[ij]][h])
__global__ __launch_bounds__(256) void bias_kernel(
    const float* __restrict__ t2, const int* __restrict__ idx,
    float* __restrict__ bias12)
{
    const int h = blockIdx.y;
    const int ij = blockIdx.x * 256 + threadIdx.x;   // 81*256 = 20736 exact
    const float b = t2[idx[ij] * 12 + h];
    bias12[h * 20736 + ij] = 16.f / (1.f + __expf(-b));
}

// ---------------------------------------------------------- f32 -> bf16 -----
__global__ __launch_bounds__(256) void convert_bf16(
    const float* __restrict__ X, unsigned short* __restrict__ Xb, long n8)
{
    long i = (long)blockIdx.x * 256 + threadIdx.x;
    const long stride = (long)gridDim.x * 256;
    for (; i < n8; i += stride) {
        const float4 v0 = ((const float4*)X)[2 * i];
        const float4 v1 = ((const float4*)X)[2 * i + 1];
        s16x8 p;
        p[0] = (short)f2bf(v0.x); p[1] = (short)f2bf(v0.y);
        p[2] = (short)f2bf(v0.z); p[3] = (short)f2bf(v0.w);
        p[4] = (short)f2bf(v1.x); p[5] = (short)f2bf(v1.y);
        p[6] = (short)f2bf(v1.z); p[7] = (short)f2bf(v1.w);
        ((s16x8*)Xb)[i] = p;
    }
}

// -------------------------------------- W[k][n] f32 -> Wt[n][k] bf16 --------
__global__ __launch_bounds__(256) void convert_transpose(
    const float* __restrict__ W, unsigned short* __restrict__ Wt, int K, int Nn)
{
    __shared__ float t[32][33];
    const int kb = blockIdx.y * 32, nb = blockIdx.x * 32;
    const int tx = threadIdx.x & 31, ty = threadIdx.x >> 5;   // ty 0..7
#pragma unroll
    for (int i = 0; i < 4; i++)
        t[ty + i * 8][tx] = W[(size_t)(kb + ty + i * 8) * Nn + nb + tx];
    __syncthreads();
#pragma unroll
    for (int i = 0; i < 4; i++) {
        const int n = ty + i * 8;
        Wt[(size_t)(nb + n) * K + kb + tx] = f2bf(t[tx][n]);
    }
}

// ---------------------------------------------------------------- QKV GEMM --
// A[73728][384] bf16 @ Bt[1152][384] bf16 (B pre-transposed) + bias
// -> Q/K/V [512][12][144][32] bf16.  m97 structure: 128^2 tile, BK=32.
__global__ __launch_bounds__(256) void qkv_gemm(
    const unsigned short* __restrict__ A, const unsigned short* __restrict__ Bt,
    const float* __restrict__ Bias,
    unsigned short* __restrict__ Qw, unsigned short* __restrict__ Kw,
    unsigned short* __restrict__ Vw)
{
    __shared__ unsigned short As[128 * 32];
    __shared__ unsigned short Bs[128 * 32];
    const int tid = threadIdx.x, lane = tid & 63, wv = tid >> 6;
    const int wm = wv >> 1, wn = wv & 1;
    const int rr = lane & 15, g = lane >> 4;
    const int mb = blockIdx.y * 128, nb = blockIdx.x * 128;

    // staging: call c of wave wv covers rows (wv*2+c)*16 .. +15; lane l -> row l/4, col (l&3)*8
    const int srow = lane >> 2, scol = (lane & 3) * 8;
    const unsigned short* aP = A + (size_t)(mb + wv * 32 + srow) * 384 + scol;
    const unsigned short* bP = Bt + (size_t)(nb + wv * 32 + srow) * 384 + scol;
    unsigned short* lA = As + wv * 1024;            // (wv*2)*512 elements
    unsigned short* lB = Bs + wv * 1024;

    f32x4 acc[4][4] = {};

    for (int kb = 0; kb < 384; kb += 32) {
        gload16(aP + kb, lA);
        gload16(aP + 16 * 384 + kb, lA + 512);
        gload16(bP + kb, lB);
        gload16(bP + 16 * 384 + kb, lB + 512);
        __syncthreads();
        s16x8 a[4], b[4];
#pragma unroll
        for (int i = 0; i < 4; i++)
            a[i] = *(const s16x8*)&As[(wm * 64 + i * 16 + rr) * 32 + g * 8];
#pragma unroll
        for (int j = 0; j < 4; j++)
            b[j] = *(const s16x8*)&Bs[(wn * 64 + j * 16 + rr) * 32 + g * 8];
#pragma unroll
        for (int i = 0; i < 4; i++)
#pragma unroll
            for (int j = 0; j < 4; j++)
                acc[i][j] = MFMA16(a[i], b[j], acc[i][j]);
        __syncthreads();
    }

#pragma unroll
    for (int i = 0; i < 4; i++) {
#pragma unroll
        for (int j = 0; j < 4; j++) {
            const int c = nb + wn * 64 + j * 16 + rr;
            const int which = c / 384;
            const int rem = c - which * 384;
            const int h = rem >> 5, d = rem & 31;
            unsigned short* dst = (which == 0) ? Qw : ((which == 1) ? Kw : Vw);
            const float bias = Bias[c];
#pragma unroll
            for (int r = 0; r < 4; r++) {
                const int m = mb + wm * 64 + i * 16 + g * 4 + r;
                const int bb = m / 144;
                const int n = m - bb * 144;
                dst[(((size_t)bb * 12 + h) * 144 + n) * 32 + d] = f2bf(acc[i][j][r] + bias);
            }
        }
    }
}

// ---------------------------------------------------------------- Proj GEMM -
// A[73728][384] bf16 @ Pt[384][384] bf16 + bias -> f32 out
__global__ __launch_bounds__(256) void proj_gemm(
    const unsigned short* __restrict__ A, const unsigned short* __restrict__ Bt,
    const float* __restrict__ Bias, float* __restrict__ Out)
{
    __shared__ unsigned short As[128 * 32];
    __shared__ unsigned short Bs[128 * 32];
    const int tid = threadIdx.x, lane = tid & 63, wv = tid >> 6;
    const int wm = wv >> 1, wn = wv & 1;
    const int rr = lane & 15, g = lane >> 4;
    const int mb = blockIdx.y * 128, nb = blockIdx.x * 128;

    const int srow = lane >> 2, scol = (lane & 3) * 8;
    const unsigned short* aP = A + (size_t)(mb + wv * 32 + srow) * 384 + scol;
    const unsigned short* bP = Bt + (size_t)(nb + wv * 32 + srow) * 384 + scol;
    unsigned short* lA = As + wv * 1024;
    unsigned short* lB = Bs + wv * 1024;

    f32x4 acc[4][4] = {};

    for (int kb = 0; kb < 384; kb += 32) {
        gload16(aP + kb, lA);
        gload16(aP + 16 * 384 + kb, lA + 512);
        gload16(bP + kb, lB);
        gload16(bP + 16 * 384 + kb, lB + 512);
        __syncthreads();
        s16x8 a[4], b[4];
#pragma unroll
        for (int i = 0; i < 4; i++)
            a[i] = *(const s16x8*)&As[(wm * 64 + i * 16 + rr) * 32 + g * 8];
#pragma unroll
        for (int j = 0; j < 4; j++)
            b[j] = *(const s16x8*)&Bs[(wn * 64 + j * 16 + rr) * 32 + g * 8];
#pragma unroll
        for (int i = 0; i < 4; i++)
#pragma unroll
            for (int j = 0; j < 4; j++)
                acc[i][j] = MFMA16(a[i], b[j], acc[i][j]);
        __syncthreads();
    }

#pragma unroll
    for (int i = 0; i < 4; i++) {
#pragma unroll
        for (int j = 0; j < 4; j++) {
            const int c = nb + wn * 64 + j * 16 + rr;
            const float bias = Bias[c];
#pragma unroll
            for (int r = 0; r < 4; r++) {
                const int m = mb + wm * 64 + i * 16 + g * 4 + r;
                Out[(size_t)m * 384 + c] = acc[i][j][r] + bias;
            }
        }
    }
}

// ---------------------------------------------------------------- Attention -
// one block per (b,h); 9 waves; wave w owns query rows 16w..16w+15
__global__ __launch_bounds__(576) void attn_kernel(
    const unsigned short* __restrict__ Qw, const unsigned short* __restrict__ Kw,
    const unsigned short* __restrict__ Vw,
    const float* __restrict__ mask,          // [64][144][144]
    const float* __restrict__ logit_scale,   // [12]
    const float* __restrict__ bias12,        // [12][144*144]
    unsigned short* __restrict__ Ow)         // [73728][384] bf16
{
    __shared__ unsigned short Qs[144][40];
    __shared__ unsigned short Ks[144][40];
    __shared__ unsigned short Vt[32][168];   // transposed V: [d][j]
    __shared__ unsigned short Ps[9][16][40];
    __shared__ float qin[144], kin[144];

    const int blk = blockIdx.x;
    const int b = blk / 12, h = blk - (blk / 12) * 12;
    const int tid = threadIdx.x;
    const int wv = tid >> 6, lane = tid & 63;
    const int rr = lane & 15, g = lane >> 4, ko = g * 8;

    const size_t base = ((size_t)b * 12 + h) * 4608;
    // staging: thread t loads elements 8t..8t+7 -> row t>>2, col (t&3)*8
    const int srow = tid >> 2, scol = (tid & 3) * 8;
    const uint4 qv = *(const uint4*)(Qw + base + tid * 8);
    const uint4 kv = *(const uint4*)(Kw + base + tid * 8);
    const uint4 vv = *(const uint4*)(Vw + base + tid * 8);
    *(uint4*)&Qs[srow][scol] = qv;
    *(uint4*)&Ks[srow][scol] = kv;
    {
        const unsigned short* vp = (const unsigned short*)&vv;
#pragma unroll
        for (int i = 0; i < 8; i++) Vt[scol + i][srow] = vp[i];
    }
    if (tid < 512) Vt[tid >> 4][144 + (tid & 15)] = 0;   // zero k-pad

    // row norms from registers (4 threads per row, shfl-reduce)
    {
        const unsigned short* qp = (const unsigned short*)&qv;
        const unsigned short* kp = (const unsigned short*)&kv;
        float qss = 0.f, kss = 0.f;
#pragma unroll
        for (int i = 0; i < 8; i++) {
            const float qf = bf2f(qp[i]), kf = bf2f(kp[i]);
            qss += qf * qf; kss += kf * kf;
        }
        qss += __shfl_xor(qss, 1, 64); qss += __shfl_xor(qss, 2, 64);
        kss += __shfl_xor(kss, 1, 64); kss += __shfl_xor(kss, 2, 64);
        if ((lane & 3) == 0) {
            const float lsv = __expf(fminf(logit_scale[h], 4.60517019f)); // log(100)
            qin[srow] = rsqrtf(qss) * lsv;
            kin[srow] = rsqrtf(kss);
        }
    }
    __syncthreads();

    // ---- S = q . k^T (unnormalized), 9 col tiles
    const s16x8 aq = *(const s16x8*)&Qs[wv * 16 + rr][ko];
    f32x4 s[9];
#pragma unroll
    for (int j = 0; j < 9; j++) {
        const s16x8 bkf = *(const s16x8*)&Ks[j * 16 + rr][ko];
        f32x4 z{};
        s[j] = MFMA16(aq, bkf, z);
    }

    // ---- softmax (logit = S*qin*kin + bias12 + mask)
    const float* mrow = mask + (size_t)(b & 63) * 20736;
    const float* brow = bias12 + h * 20736;
    const int rowbase = wv * 16 + g * 4;
    float pv[4][9];
    float invsum[4];
#pragma unroll
    for (int r = 0; r < 4; r++) {
        const int ri = rowbase + r;
        const float qi = qin[ri];
        float lg[9];
        float mx = -3.0e38f;
#pragma unroll
        for (int j = 0; j < 9; j++) {
            const int cj = j * 16 + rr;
            const float lv = s[j][r] * qi * kin[cj] + brow[ri * 144 + cj] + mrow[ri * 144 + cj];
            lg[j] = lv;
            mx = fmaxf(mx, lv);
        }
#pragma unroll
        for (int o = 1; o < 16; o <<= 1) mx = fmaxf(mx, __shfl_xor(mx, o, 64));
        float sm = 0.f;
#pragma unroll
        for (int j = 0; j < 9; j++) {
            const float p = __expf(lg[j] - mx);
            pv[r][j] = p;
            sm += p;
        }
#pragma unroll
        for (int o = 1; o < 16; o <<= 1) sm += __shfl_xor(sm, o, 64);
        invsum[r] = 1.f / sm;
    }

    // ---- PV
    f32x4 o0{}, o1{};
#pragma unroll
    for (int kt = 0; kt < 5; kt++) {
#pragma unroll
        for (int jj = 0; jj < 2; jj++) {
            const int j = 2 * kt + jj;
#pragma unroll
            for (int r = 0; r < 4; r++) {
                const unsigned short val = (j < 9) ? f2bf(pv[r][j]) : (unsigned short)0;
                Ps[wv][g * 4 + r][jj * 16 + rr] = val;
            }
        }
        const s16x8 pa  = *(const s16x8*)&Ps[wv][rr][ko];
        const s16x8 vb0 = *(const s16x8*)&Vt[rr][kt * 32 + ko];
        const s16x8 vb1 = *(const s16x8*)&Vt[16 + rr][kt * 32 + ko];
        o0 = MFMA16(pa, vb0, o0);
        o1 = MFMA16(pa, vb1, o1);
    }

#pragma unroll
    for (int r = 0; r < 4; r++) {
        const int ri = rowbase + r;
        const size_t orow = ((size_t)b * 144 + ri) * 384 + h * 32;
        Ow[orow + rr]      = f2bf(o0[r] * invsum[r]);
        Ow[orow + 16 + rr] = f2bf(o1[r] * invsum[r]);
    }
}

// ---------------------------------------------------------------- launch ----
extern "C" void kernel_launch(void* const* d_in, const int* in_sizes, int n_in,
                              void* d_out, int out_size, void* d_ws, size_t ws_size,
                              hipStream_t stream)
{
    (void)in_sizes; (void)n_in; (void)out_size; (void)ws_size;
    const float* x           = (const float*)d_in[0];
    const float* mask        = (const float*)d_in[1];
    const float* qkv_w       = (const float*)d_in[2];
    const float* qkv_b       = (const float*)d_in[3];
    const float* proj_w      = (const float*)d_in[4];
    const float* proj_b      = (const float*)d_in[5];
    const float* cpb_w1      = (const float*)d_in[6];
    const float* cpb_b1      = (const float*)d_in[7];
    const float* cpb_w2      = (const float*)d_in[8];
    const float* logit_scale = (const float*)d_in[9];
    const float* tbl         = (const float*)d_in[10];
    const int*   idx         = (const int*)d_in[11];

    char* ws = (char*)d_ws;
    const size_t QBYTES = (size_t)512 * 12 * 144 * 32 * 2;   // 56,623,104
    float* t2           = (float*)ws;                         // 32 KB slot
    float* bias12       = (float*)(ws + 32768);               // 995 KB -> 1 MB slot
    unsigned short* Wb  = (unsigned short*)(ws + 32768 + 1048576);          // 884,736 -> 917,504
    unsigned short* Pb  = (unsigned short*)(ws + 32768 + 1048576 + 917504); // 294,912 -> 327,680
    char* big = ws + 32768 + 1048576 + 917504 + 327680;       // 2,326,528
    unsigned short* Qw = (unsigned short*)big;
    unsigned short* Kw = (unsigned short*)(big + QBYTES);
    unsigned short* Vw = (unsigned short*)(big + 2 * QBYTES);
    unsigned short* Ow = (unsigned short*)(big + 3 * QBYTES); // also aliases Xb (bf16 X)
    unsigned short* Xb = Ow;  // X-bf16 lives here until attn overwrites with O

    cpb_kernel<<<529, 128, 0, stream>>>(tbl, cpb_w1, cpb_b1, cpb_w2, t2);
    bias_kernel<<<dim3(81, 12), 256, 0, stream>>>(t2, idx, bias12);
    convert_bf16<<<2048, 256, 0, stream>>>(x, Xb, (long)73728 * 384 / 8);
    convert_transpose<<<dim3(36, 12), 256, 0, stream>>>(qkv_w, Wb, 384, 1152);
    convert_transpose<<<dim3(12, 12), 256, 0, stream>>>(proj_w, Pb, 384, 384);
    qkv_gemm<<<dim3(9, 576), 256, 0, stream>>>(Xb, Wb, qkv_b, Qw, Kw, Vw);
    attn_kernel<<<6144, 576, 0, stream>>>(Qw, Kw, Vw, mask, logit_scale, bias12, Ow);
    proj_gemm<<<dim3(3, 576), 256, 0, stream>>>(Ow, Pb, proj_b, (float*)d_out);
}